// Round 7
// baseline (254.798 us; speedup 1.0000x reference)
//
#include <hip/hip_runtime.h>
#include <stdint.h>

#define FD 2048
#define BK 256

typedef short short8 __attribute__((ext_vector_type(8)));
typedef float f32x4 __attribute__((ext_vector_type(4)));
typedef unsigned short ushort_t;
typedef __attribute__((address_space(3))) char lds_char;
typedef __attribute__((address_space(1))) const char glb_char;

__device__ __forceinline__ unsigned bf16_rne(float f) {
  unsigned u = __float_as_uint(f);
  return (u + 0x7FFFu + ((u >> 16) & 1u)) >> 16;
}

// ---- prep: build v_hi/v_lo bf16 fragments in MFMA B-layout + S2 table ----
__global__ __launch_bounds__(256) void fm_prep(
    const float* __restrict__ v, ushort_t* __restrict__ hi,
    ushort_t* __restrict__ lo, float* __restrict__ s2t)
{
  int bid = blockIdx.x;
  if (bid < 512) {
    int t = bid * 256 + threadIdx.x;       // bf16 element index 0..131071
    int j    = t & 7;
    int lane = (t >> 3) & 63;
    int c    = (t >> 9) & 3;
    int s    = t >> 11;
    int k    = s * 32 + ((lane >> 4) << 3) + j;
    int col  = (c << 4) + (lane & 15);
    float val = v[k * 64 + col];
    unsigned hb = bf16_rne(val);
    float hf = __uint_as_float(hb << 16);
    unsigned lb = bf16_rne(val - hf);
    hi[t] = (ushort_t)hb;
    lo[t] = (ushort_t)lb;
  } else {
    int k = (bid - 512) * 256 + threadIdx.x;   // 0..2047
    const float4* row = (const float4*)(v + k * 64);
    float s = 0.f;
    #pragma unroll
    for (int i = 0; i < 16; ++i) {
      float4 q = row[i];
      s += q.x * q.x + q.y * q.y + q.z * q.z + q.w * q.w;
    }
    s2t[k] = s;
  }
}

// convert 8 floats -> hi/lo bf16 fragments (scalar RNE), accumulate lin/q
__device__ __forceinline__ void cvt_row(
    const f32x4& A0, const f32x4& A1,
    const f32x4& W0v, const f32x4& W1v,
    const f32x4& S0, const f32x4& S1,
    short8& H, short8& L, float& lin, float& q)
{
  #pragma unroll
  for (int j = 0; j < 8; ++j) {
    float f  = (j < 4) ? A0[j & 3] : A1[j & 3];
    float fw = (j < 4) ? W0v[j & 3] : W1v[j & 3];
    float fs = (j < 4) ? S0[j & 3] : S1[j & 3];
    unsigned h = bf16_rne(f);
    H[j] = (short)h;
    L[j] = (short)bf16_rne(f - __uint_as_float(h << 16));
    lin = fmaf(f, fw, lin);
    q   = fmaf(f * f, fs, q);
  }
}

#define MF(accv, a, b) accv = __builtin_amdgcn_mfma_f32_16x16x32_bf16(a, b, accv, 0, 0, 0)

// ---- main: 512 WGs x 512 thr (8 waves); WG = 32 rows, K tiled at BK=256.
// Per tile t: wave w STAGES rows 4w..4w+3 of tile t+1 (global_load_lds,
// XOR-swizzled source, linear LDS dest) and COMPUTES k-slice s=8t+w from
// the staged tile t. One __syncthreads per tile.
__global__ __launch_bounds__(512, 4) void fm_main(
    const float* __restrict__ x, const float* __restrict__ w,
    const float* __restrict__ bptr, const short8* __restrict__ vhi,
    const short8* __restrict__ vlo, const float* __restrict__ s2t,
    float* __restrict__ out)
{
  __shared__ float xbuf[2][32][BK];   // 64 KB double-buffered x tile
  __shared__ float lds_xv[32][64];
  __shared__ float lds_lin[32];
  __shared__ float lds_q[32];

  const int tid = threadIdx.x;
  const int wid = tid >> 6;        // 0..7: stage-rows 4w..4w+3, k-slice w
  const int l   = tid & 63;
  const int l15 = l & 15;
  const int lk  = l >> 4;          // 0..3 k-group
  const int l4  = l << 4;          // lane byte granule
  const int R   = blockIdx.x << 5; // 32 rows per WG

  // stage 4 rows of x-tile `t` into xbuf[b] (linear LDS dest, swizzled src)
  #define STAGE(t, b)                                                        \
    {                                                                        \
      _Pragma("unroll")                                                      \
      for (int j = 0; j < 4; ++j) {                                          \
        const int row = (wid << 2) + j;                                      \
        const char* src = (const char*)x +                                   \
            (((size_t)(R + row) << 11) + ((size_t)(t) << 8)) * 4 +           \
            (size_t)(l4 ^ ((row & 7) << 4));                                 \
        char* dst = (char*)&xbuf[b][row][0];                                 \
        __builtin_amdgcn_global_load_lds((glb_char*)src, (lds_char*)dst,     \
                                         16, 0, 0);                          \
      }                                                                      \
    }

  {
    float* z = &lds_xv[0][0];
    #pragma unroll
    for (int i = tid; i < 32 * 64; i += 512) z[i] = 0.f;
    if (tid < 32) { lds_lin[tid] = 0.f; lds_q[tid] = 0.f; }
  }
  STAGE(0, 0);
  __syncthreads();   // vmcnt(0) drain: tile 0 staged, xv zeroed

  f32x4 acc[2][4];
  #pragma unroll
  for (int t = 0; t < 2; ++t)
    #pragma unroll
    for (int c = 0; c < 4; ++c)
      acc[t][c] = (f32x4){0.f, 0.f, 0.f, 0.f};
  float lin0 = 0.f, lin1 = 0.f, q0 = 0.f, q1 = 0.f;

  const int sw  = (l15 & 7) << 4;              // read-side XOR (row&7==l15&7)
  const int cb0 = (wid << 7) + (lk << 5);      // byte col of this wave's k-slice

  #pragma unroll 1
  for (int t = 0; t < 8; ++t) {
    const int b = t & 1;

    // ---- oldest VM ops: w/s2 (consumed by cvt), then B frags (L2-hot)
    const int wo = (t << 8) + (wid << 5) + (lk << 3);
    f32x4 wa = *(const f32x4*)(w + wo);
    f32x4 wb = *(const f32x4*)(w + wo + 4);
    f32x4 sa = *(const f32x4*)(s2t + wo);
    f32x4 sb = *(const f32x4*)(s2t + wo + 4);
    const short8* pb = vhi + ((size_t)(((t << 3) + wid) << 2) << 6) / 64 * 64; // (s*4)*64
    const short8* plv = vlo + (size_t)(((t << 3) + wid) << 2) * 64;
    const short8* pbv = vhi + (size_t)(((t << 3) + wid) << 2) * 64;
    short8 bh0 = pbv[l];        short8 bh1 = pbv[64 + l];
    short8 bh2 = pbv[128 + l];  short8 bh3 = pbv[192 + l];
    short8 bl0 = plv[l];        short8 bl1 = plv[64 + l];
    short8 bl2 = plv[128 + l];  short8 bl3 = plv[192 + l];

    // ---- newest VM ops: stage next tile (never drained by B's counted wait)
    if (t < 7) STAGE(t + 1, b ^ 1);

    // ---- row-group 0: rows l15
    {
      const char* base = (const char*)&xbuf[b][l15][0];
      f32x4 a0 = *(const f32x4*)(base + (cb0 ^ sw));
      f32x4 a1 = *(const f32x4*)(base + ((cb0 + 16) ^ sw));
      short8 cah, cal;
      cvt_row(a0, a1, wa, wb, sa, sb, cah, cal, lin0, q0);
      MF(acc[0][0], cah, bh0); MF(acc[0][1], cah, bh1);
      MF(acc[0][2], cah, bh2); MF(acc[0][3], cah, bh3);
      MF(acc[0][0], cal, bh0); MF(acc[0][1], cal, bh1);
      MF(acc[0][2], cal, bh2); MF(acc[0][3], cal, bh3);
      MF(acc[0][0], cah, bl0); MF(acc[0][1], cah, bl1);
      MF(acc[0][2], cah, bl2); MF(acc[0][3], cah, bl3);
    }
    // ---- row-group 1: rows l15+16 (same XOR: (l15+16)&7 == l15&7)
    {
      const char* base = (const char*)&xbuf[b][l15 + 16][0];
      f32x4 a0 = *(const f32x4*)(base + (cb0 ^ sw));
      f32x4 a1 = *(const f32x4*)(base + ((cb0 + 16) ^ sw));
      short8 cah, cal;
      cvt_row(a0, a1, wa, wb, sa, sb, cah, cal, lin1, q1);
      MF(acc[1][0], cah, bh0); MF(acc[1][1], cah, bh1);
      MF(acc[1][2], cah, bh2); MF(acc[1][3], cah, bh3);
      MF(acc[1][0], cal, bh0); MF(acc[1][1], cal, bh1);
      MF(acc[1][2], cal, bh2); MF(acc[1][3], cal, bh3);
      MF(acc[1][0], cah, bl0); MF(acc[1][1], cah, bl1);
      MF(acc[1][2], cah, bl2); MF(acc[1][3], cah, bl3);
    }

    __syncthreads();   // buffer swap; drains stage(t+1) after a full tile of cover
  }

  // reduce lin/q over the 4 k-groups sharing a row (lanes l ^ {16,32})
  lin0 += __shfl_xor(lin0, 16, 64); lin0 += __shfl_xor(lin0, 32, 64);
  lin1 += __shfl_xor(lin1, 16, 64); lin1 += __shfl_xor(lin1, 32, 64);
  q0   += __shfl_xor(q0,   16, 64); q0   += __shfl_xor(q0,   32, 64);
  q1   += __shfl_xor(q1,   16, 64); q1   += __shfl_xor(q1,   32, 64);
  if (lk == 0) {
    atomicAdd(&lds_lin[l15],      lin0);
    atomicAdd(&lds_lin[16 + l15], lin1);
    atomicAdd(&lds_q[l15],        q0);
    atomicAdd(&lds_q[16 + l15],   q1);
  }

  // accumulate partial xv into LDS (C/D layout: col=l&15, row=(l>>4)*4+j)
  #pragma unroll
  for (int t = 0; t < 2; ++t)
    #pragma unroll
    for (int c = 0; c < 4; ++c)
      #pragma unroll
      for (int j = 0; j < 4; ++j)
        atomicAdd(&lds_xv[t * 16 + (lk << 2) + j][(c << 4) + l15], acc[t][c][j]);

  __syncthreads();

  // final: thread -> (row = tid>>4, colgroup = tid&15); reduce cols, sigmoid
  {
    const int row = tid >> 4;
    const int cg  = tid & 15;
    float4 s = *(const float4*)&lds_xv[row][cg << 2];
    float ss = s.x * s.x + s.y * s.y + s.z * s.z + s.w * s.w;
    ss += __shfl_xor(ss, 1, 64);
    ss += __shfl_xor(ss, 2, 64);
    ss += __shfl_xor(ss, 4, 64);
    ss += __shfl_xor(ss, 8, 64);
    if (cg == 0) {
      float zz = lds_lin[row] + bptr[0] + 0.5f * (ss - lds_q[row]);
      out[R + row] = 1.f / (1.f + expf(-zz));
    }
  }
  #undef STAGE
}

extern "C" void kernel_launch(void* const* d_in, const int* in_sizes, int n_in,
                              void* d_out, int out_size, void* d_ws, size_t ws_size,
                              hipStream_t stream) {
  const float* x = (const float*)d_in[0];
  const float* w = (const float*)d_in[1];
  const float* b = (const float*)d_in[2];
  const float* v = (const float*)d_in[3];
  float* out = (float*)d_out;

  // ws layout: [0,256K) v_hi bf16 frags | [256K,512K) v_lo | [512K,520K) S2 f32
  ushort_t* hi = (ushort_t*)d_ws;
  ushort_t* lo = hi + FD * 64;
  float*    s2 = (float*)((char*)d_ws + (size_t)FD * 64 * 2 * sizeof(ushort_t));

  fm_prep<<<520, 256, 0, stream>>>(v, hi, lo, s2);
  fm_main<<<512, 512, 0, stream>>>(x, w, b, (const short8*)hi, (const short8*)lo, s2, out);
}